// Round 4
// baseline (1101.664 us; speedup 1.0000x reference)
//
#include <hip/hip_runtime.h>
#include <cstdint>
#include <cmath>

#define T_TOK 8192
#define H_DIM 1024
#define F_DIM 4096
#define NE 8
#define CAP 8192        // perm capacity per expert
#define BM 256
#define BN 256
#define BK 64
#define MBLK 16         // max M-blocks per expert (4096-token cap)
#define KSPLIT 2        // gemm2 split-K chunks
#define NWORK 256       // persistent blocks (1 per CU)

typedef __attribute__((ext_vector_type(8))) short short8v;
typedef __attribute__((ext_vector_type(4))) float f32x4;

static __device__ __forceinline__ unsigned short f2bf(float f) {
    union { float f; unsigned int u; } v; v.f = f;
    unsigned int r = v.u + 0x7FFFu + ((v.u >> 16) & 1u);  // RNE
    return (unsigned short)(r >> 16);
}

// async global->LDS, 16B per lane; LDS dest is wave-uniform base + lane*16,
// global src is per-lane (supports gather + pre-swizzled source).
static __device__ __forceinline__ void gl_lds16(const void* g, void* l) {
    __builtin_amdgcn_global_load_lds(
        (const __attribute__((address_space(1))) unsigned int*)g,
        (__attribute__((address_space(3))) unsigned int*)l, 16, 0, 0);
}

#define WAITV8 do { asm volatile("s_waitcnt vmcnt(8)" ::: "memory"); \
                    __builtin_amdgcn_sched_barrier(0); } while (0)
#define WAITV0 do { asm volatile("s_waitcnt vmcnt(0)" ::: "memory"); \
                    __builtin_amdgcn_sched_barrier(0); } while (0)
#define BARRIER do { __builtin_amdgcn_s_barrier(); \
                     __builtin_amdgcn_sched_barrier(0); } while (0)

// ---------------- router: logits, top-2, weights, compaction, + x->bf16 ----------------
__global__ void router_k(const float* __restrict__ x, const float* __restrict__ Wr,
                         const float* __restrict__ br,
                         int* __restrict__ cnt, int* __restrict__ perm, float* __restrict__ pw,
                         unsigned short* __restrict__ xb)
{
    const int wave = threadIdx.x >> 6;
    const int lane = threadIdx.x & 63;
    const int t = blockIdx.x * 4 + wave;
    const float* xr = x + (size_t)t * H_DIM;
    float acc[NE];
#pragma unroll
    for (int e = 0; e < NE; ++e) acc[e] = 0.f;
#pragma unroll
    for (int c0 = 0; c0 < H_DIM; c0 += 256) {
        const float4 v = *(const float4*)(xr + c0 + lane * 4);
        ushort4 ob;
        ob.x = f2bf(v.x); ob.y = f2bf(v.y); ob.z = f2bf(v.z); ob.w = f2bf(v.w);
        *(ushort4*)(xb + (size_t)t * H_DIM + c0 + lane * 4) = ob;
        const int hbase = c0 + lane * 4;
        float vv[4] = {v.x, v.y, v.z, v.w};
#pragma unroll
        for (int i = 0; i < 4; ++i) {
            const float4 w0 = *(const float4*)(Wr + (size_t)(hbase + i) * NE);
            const float4 w1 = *(const float4*)(Wr + (size_t)(hbase + i) * NE + 4);
            acc[0] += vv[i] * w0.x; acc[1] += vv[i] * w0.y;
            acc[2] += vv[i] * w0.z; acc[3] += vv[i] * w0.w;
            acc[4] += vv[i] * w1.x; acc[5] += vv[i] * w1.y;
            acc[6] += vv[i] * w1.z; acc[7] += vv[i] * w1.w;
        }
    }
#pragma unroll
    for (int off = 32; off > 0; off >>= 1) {
#pragma unroll
        for (int e = 0; e < NE; ++e) acc[e] += __shfl_xor(acc[e], off, 64);
    }
    if (lane == 0) {
#pragma unroll
        for (int e = 0; e < NE; ++e) acc[e] += br[e];
        int i0 = 0; float l0 = acc[0];
#pragma unroll
        for (int e = 1; e < NE; ++e) if (acc[e] > l0) { l0 = acc[e]; i0 = e; }
        int i1 = -1; float l1 = -3.4e38f;
#pragma unroll
        for (int e = 0; e < NE; ++e) if (e != i0 && acc[e] > l1) { l1 = acc[e]; i1 = e; }
        const float w0 = 1.f / (1.f + expf(l1 - l0));
        const int p0 = atomicAdd(&cnt[i0], 1);
        perm[i0 * CAP + p0] = t; pw[i0 * CAP + p0] = w0;
        const int p1 = atomicAdd(&cnt[i1], 1);
        perm[i1 * CAP + p1] = t; pw[i1 * CAP + p1] = 1.f - w0;
    }
}

// ---------------- prefix + compacted tile list ----------------
// offs[e]: 256-aligned row offsets; mlist[i] = (e<<8)|mb for each active M-block;
// meta[0] = ntiles_gemm1 = nmb*16; meta[1] = ntiles_gemm2 = nmb*4*KSPLIT.
__global__ void prefix_k(const int* __restrict__ cnt, int* __restrict__ offs,
                         int* __restrict__ mlist, int* __restrict__ meta)
{
    if (threadIdx.x == 0 && blockIdx.x == 0) {
        int o = 0, nmb = 0;
        for (int e = 0; e < NE; ++e) {
            offs[e] = o;
            int mb = (cnt[e] + BM - 1) >> 8;
            if (mb > MBLK) mb = MBLK;
            for (int m = 0; m < mb; ++m) mlist[nmb++] = (e << 8) | m;
            o += mb << 8;
        }
        offs[NE] = o;
        meta[0] = nmb * (F_DIM / BN);
        meta[1] = nmb * (H_DIM / BN) * KSPLIT;
    }
}

// ---------------- transpose + fp32->bf16 convert: in[E][R][C] -> out[E][C][R] ----------------
__global__ __launch_bounds__(256) void tcvt_k(const float* __restrict__ in,
                                              unsigned short* __restrict__ out,
                                              int R, int C)
{
    __shared__ float tile[64][65];
    const int e = blockIdx.z;
    const int r0 = blockIdx.y * 64, c0 = blockIdx.x * 64;
    const float* ip = in + (size_t)e * R * C;
    unsigned short* op = out + (size_t)e * R * C;
    const int j = threadIdx.x;
    const int lr = j >> 4, lc = (j & 15) * 4;
#pragma unroll
    for (int p = 0; p < 4; ++p) {
        const float4 v = *(const float4*)(ip + (size_t)(r0 + lr + p * 16) * C + c0 + lc);
        tile[lr + p * 16][lc + 0] = v.x;
        tile[lr + p * 16][lc + 1] = v.y;
        tile[lr + p * 16][lc + 2] = v.z;
        tile[lr + p * 16][lc + 3] = v.w;
    }
    __syncthreads();
#pragma unroll
    for (int p = 0; p < 4; ++p) {
        const int orow = lr + p * 16;
        ushort4 o;
        o.x = f2bf(tile[lc + 0][orow]);
        o.y = f2bf(tile[lc + 1][orow]);
        o.z = f2bf(tile[lc + 2][orow]);
        o.w = f2bf(tile[lc + 3][orow]);
        *(ushort4*)(op + (size_t)(c0 + orow) * R + r0 + lc) = o;
    }
}

// shared GEMM-core macros (256x256 tile, 8 waves, dbuf counted-vmcnt schedule)
#define STAGE(tt, kb) do {                                                      \
    const int _o = ((tt) & 1) << 15;                                            \
    const int _k = (kb) + (tt) * BK;                                            \
    _Pragma("unroll") for (int j = 0; j < 4; ++j)                               \
        gl_lds16(srcA[j] + _k, smem + _o + dstA[j]);                            \
    _Pragma("unroll") for (int j = 0; j < 4; ++j)                               \
        gl_lds16(srcB[j] + _k, smem + _o + dstB[j]);                            \
} while (0)

#define COMPUTE(tt) do {                                                        \
    const unsigned short* _A = smem + (((tt) & 1) << 15);                       \
    const unsigned short* _B = _A + 16384;                                      \
    _Pragma("unroll") for (int kk = 0; kk < 2; ++kk) {                          \
        const int q = kk * 4 + fg;                                              \
        short8v a[8], b[4];                                                     \
        _Pragma("unroll") for (int m = 0; m < 8; ++m) {                         \
            const int R = wm * 128 + m * 16 + fr;                               \
            a[m] = *(const short8v*)(_A + R * BK + ((q ^ (R & 7)) * 8));        \
        }                                                                       \
        _Pragma("unroll") for (int n = 0; n < 4; ++n) {                         \
            const int R = wn * 64 + n * 16 + fr;                                \
            b[n] = *(const short8v*)(_B + R * BK + ((q ^ (R & 7)) * 8));        \
        }                                                                       \
        __builtin_amdgcn_s_setprio(1);                                          \
        _Pragma("unroll") for (int m = 0; m < 8; ++m)                           \
            _Pragma("unroll") for (int n = 0; n < 4; ++n)                       \
                acc[m][n] = __builtin_amdgcn_mfma_f32_16x16x32_bf16(            \
                    b[n], a[m], acc[m][n], 0, 0, 0);                            \
        __builtin_amdgcn_s_setprio(0);                                          \
    }                                                                           \
} while (0)

#define KLOOP(NT, kb) do {                                                      \
    STAGE(0, kb); STAGE(1, kb);                                                 \
    WAITV8; BARRIER;                                                            \
    for (int t = 0; t < (NT); ++t) {                                            \
        COMPUTE(t);                                                             \
        if (t == (NT) - 1) break;                                               \
        BARRIER;                                                                \
        if (t + 2 < (NT)) { STAGE(t + 2, kb); WAITV8; } else { WAITV0; }        \
        BARRIER;                                                                \
    }                                                                           \
} while (0)

// ================= GEMM1: h = gelu(gather(x) @ W1[e] + b1[e]) =================
// persistent blocks, atomic tile queue over compacted (e,mb) x nb tiles.
__global__ __launch_bounds__(512, 2) void gemm1_k(
    const unsigned short* __restrict__ xb,   // [T][H] bf16
    const unsigned short* __restrict__ w1t,  // [E][F][H] bf16 (pre-transposed)
    const float* __restrict__ b1,            // [E][F]
    unsigned short* __restrict__ hbuf,       // [rows][F] bf16
    const int* __restrict__ perm, const int* __restrict__ cnt, const int* __restrict__ offs,
    const int* __restrict__ mlist, const int* __restrict__ meta, int* __restrict__ qctr)
{
    __shared__ __align__(16) unsigned short smem[65536];   // 128KB dbuf
    __shared__ int rows_s[BM];
    __shared__ int idx_s;

    const int tid = threadIdx.x;
    const int lane = tid & 63;
    const int w = tid >> 6;
    const int srow = tid >> 3;
    const int us = ((tid & 7) ^ (srow & 7)) * 8;   // pre-swizzled source unit
    const int fr = lane & 15;
    const int fg = lane >> 4;
    const int wm = w >> 2;
    const int wn = w & 3;

    for (;;) {
        if (tid == 0) idx_s = atomicAdd(&qctr[0], 1);
        __syncthreads();
        const int idx = idx_s;
        if (idx >= meta[0]) break;

        const int mi = idx >> 4;           // /16 nb-blocks
        const int nb = idx & 15;           // nb fastest: consecutive tiles share A panel
        const int e  = mlist[mi] >> 8;
        const int mb = mlist[mi] & 255;
        const int c  = cnt[e];
        const int m0 = mb * BM;

        if (tid < BM) {
            const int i = m0 + tid;
            rows_s[tid] = perm[e * CAP + (i < c ? i : c - 1)];
        }
        __syncthreads();

        const unsigned short* bp = w1t + ((size_t)e * F_DIM + nb * BN) * H_DIM;
        const unsigned short* srcA[4];
        const unsigned short* srcB[4];
        int dstA[4], dstB[4];
#pragma unroll
        for (int j = 0; j < 4; ++j) {
            const int r = j * 64 + srow;
            srcA[j] = xb + (size_t)rows_s[r] * H_DIM + us;
            srcB[j] = bp + (size_t)r * H_DIM + us;
            dstA[j] = (j * 64 + w * 8) * BK + lane * 8;
            dstB[j] = 16384 + (j * 64 + w * 8) * BK + lane * 8;
        }

        f32x4 acc[8][4];
#pragma unroll
        for (int m = 0; m < 8; ++m)
#pragma unroll
            for (int n = 0; n < 4; ++n) acc[m][n] = (f32x4){0.f, 0.f, 0.f, 0.f};

        KLOOP(H_DIM / BK, 0);

        // epilogue: thread holds 4 consecutive f at fixed token -> packed 8B stores
        const size_t hrow0 = (size_t)offs[e] + m0;
#pragma unroll
        for (int n = 0; n < 4; ++n) {
            const int f = nb * BN + wn * 64 + n * 16 + fg * 4;
            const float4 bv = *(const float4*)(b1 + e * F_DIM + f);
            const float bb[4] = {bv.x, bv.y, bv.z, bv.w};
#pragma unroll
            for (int m = 0; m < 8; ++m) {
                const int tl = wm * 128 + m * 16 + fr;
                ushort4 o;
#pragma unroll
                for (int r = 0; r < 4; ++r) {
                    const float xv = acc[m][n][r] + bb[r];
                    const float g = 0.5f * xv * (1.f + erff(xv * 0.70710678118f));
                    ((unsigned short*)&o)[r] = f2bf(g);
                }
                *(ushort4*)(hbuf + (hrow0 + tl) * F_DIM + f) = o;
            }
        }
    }
}

// ================= GEMM2: out[t] += w * (h @ W2[e] + b2[e]), split-K =================
__global__ __launch_bounds__(512, 2) void gemm2_k(
    const unsigned short* __restrict__ hbuf, // [rows][F] bf16
    const unsigned short* __restrict__ w2t,  // [E][H][F] bf16 (pre-transposed)
    const float* __restrict__ b2,            // [E][H]
    float* __restrict__ out,                 // [T][H] fp32 (pre-zeroed)
    const int* __restrict__ perm, const float* __restrict__ pw,
    const int* __restrict__ cnt, const int* __restrict__ offs,
    const int* __restrict__ mlist, const int* __restrict__ meta, int* __restrict__ qctr)
{
    __shared__ __align__(16) unsigned short smem[65536];
    __shared__ int rows_s[BM];
    __shared__ float pw_s[BM];
    __shared__ int idx_s;

    const int tid = threadIdx.x;
    const int lane = tid & 63;
    const int w = tid >> 6;
    const int srow = tid >> 3;
    const int us = ((tid & 7) ^ (srow & 7)) * 8;
    const int fr = lane & 15;
    const int fg = lane >> 4;
    const int wm = w >> 2;
    const int wn = w & 3;

    constexpr int KC = F_DIM / KSPLIT;       // 2048 per chunk
    constexpr int NXB = H_DIM / BN;          // 4

    for (;;) {
        if (tid == 0) idx_s = atomicAdd(&qctr[1], 1);
        __syncthreads();
        const int idx = idx_s;
        if (idx >= meta[1]) break;

        const int mi = idx / (NXB * KSPLIT);
        const int r2 = idx % (NXB * KSPLIT);
        const int kc = r2 >> 2;              // chunk
        const int nb = r2 & 3;               // nb fastest: share A K-strip
        const int e  = mlist[mi] >> 8;
        const int mb = mlist[mi] & 255;
        const int c  = cnt[e];
        const int m0 = mb * BM;

        if (tid < BM) {
            const int i = m0 + tid;
            const int ic = (i < c ? i : c - 1);
            rows_s[tid] = perm[e * CAP + ic];
            pw_s[tid]   = pw[e * CAP + ic];
        }
        __syncthreads();

        const size_t arow0 = (size_t)offs[e] + m0;
        const unsigned short* bp = w2t + ((size_t)e * H_DIM + nb * BN) * F_DIM;
        const int kbase = kc * KC;
        const unsigned short* srcA[4];
        const unsigned short* srcB[4];
        int dstA[4], dstB[4];
#pragma unroll
        for (int j = 0; j < 4; ++j) {
            const int r = j * 64 + srow;
            srcA[j] = hbuf + (arow0 + r) * F_DIM + kbase + us;
            srcB[j] = bp + (size_t)r * F_DIM + kbase + us;
            dstA[j] = (j * 64 + w * 8) * BK + lane * 8;
            dstB[j] = 16384 + (j * 64 + w * 8) * BK + lane * 8;
        }

        f32x4 acc[8][4];
#pragma unroll
        for (int m = 0; m < 8; ++m)
#pragma unroll
            for (int n = 0; n < 4; ++n) acc[m][n] = (f32x4){0.f, 0.f, 0.f, 0.f};

        KLOOP(KC / BK, 0);

        // epilogue: 4 consecutive h-cols per thread; bias only in chunk 0
#pragma unroll
        for (int n = 0; n < 4; ++n) {
            const int h = nb * BN + wn * 64 + n * 16 + fg * 4;
            const float4 bv = *(const float4*)(b2 + e * H_DIM + h);
            const float bb[4] = {bv.x, bv.y, bv.z, bv.w};
#pragma unroll
            for (int m = 0; m < 8; ++m) {
                const int tl = wm * 128 + m * 16 + fr;
                if (m0 + tl < c) {
                    const int trow = rows_s[tl];
                    const float wgt = pw_s[tl];
#pragma unroll
                    for (int r = 0; r < 4; ++r) {
                        const float y = acc[m][n][r] + (kc == 0 ? bb[r] : 0.f);
                        atomicAdd(out + (size_t)trow * H_DIM + h + r, wgt * y);
                    }
                }
            }
        }
    }
}

extern "C" void kernel_launch(void* const* d_in, const int* in_sizes, int n_in,
                              void* d_out, int out_size, void* d_ws, size_t ws_size,
                              hipStream_t stream)
{
    const float* x  = (const float*)d_in[0];
    const float* Wr = (const float*)d_in[1];
    const float* br = (const float*)d_in[2];
    const float* W1 = (const float*)d_in[3];
    const float* b1 = (const float*)d_in[4];
    const float* W2 = (const float*)d_in[5];
    const float* b2 = (const float*)d_in[6];
    float* out = (float*)d_out;

    char* ws = (char*)d_ws;
    size_t off = 0;
    auto alloc = [&](size_t bytes) {
        char* p = ws + off;
        off += (bytes + 255) & ~(size_t)255;
        return p;
    };
    unsigned short* w1t  = (unsigned short*)alloc((size_t)NE * F_DIM * H_DIM * 2);  // 67 MB
    unsigned short* w2t  = (unsigned short*)alloc((size_t)NE * H_DIM * F_DIM * 2);  // 67 MB
    unsigned short* xb   = (unsigned short*)alloc((size_t)T_TOK * H_DIM * 2);       // 17 MB
    unsigned short* hbuf = (unsigned short*)alloc((size_t)(T_TOK * 2 + NE * BM) * F_DIM * 2); // 151 MB
    int*   cnt   = (int*)alloc(NE * 4);
    int*   offs  = (int*)alloc((NE + 1) * 4);
    int*   perm  = (int*)alloc((size_t)NE * CAP * 4);
    float* pw    = (float*)alloc((size_t)NE * CAP * 4);
    int*   mlist = (int*)alloc(NE * MBLK * 4);
    int*   meta  = (int*)alloc(2 * 4);
    int*   qctr  = (int*)alloc(2 * 4);
    (void)ws_size; (void)in_sizes; (void)n_in; (void)out_size;

    hipMemsetAsync(cnt, 0, NE * 4, stream);
    hipMemsetAsync(qctr, 0, 2 * 4, stream);
    router_k<<<T_TOK / 4, 256, 0, stream>>>(x, Wr, br, cnt, perm, pw, xb);
    prefix_k<<<1, 64, 0, stream>>>(cnt, offs, mlist, meta);
    tcvt_k<<<dim3(F_DIM / 64, H_DIM / 64, NE), 256, 0, stream>>>(W1, w1t, H_DIM, F_DIM);
    tcvt_k<<<dim3(H_DIM / 64, F_DIM / 64, NE), 256, 0, stream>>>(W2, w2t, F_DIM, H_DIM);
    gemm1_k<<<NWORK, 512, 0, stream>>>(xb, w1t, b1, hbuf, perm, cnt, offs, mlist, meta, qctr);
    hipMemsetAsync(out, 0, (size_t)T_TOK * H_DIM * 4, stream);
    gemm2_k<<<NWORK, 512, 0, stream>>>(hbuf, w2t, b2, out, perm, pw, cnt, offs, mlist, meta, qctr);
}

// Round 5
// 816.191 us; speedup vs baseline: 1.3498x; 1.3498x over previous
//
#include <hip/hip_runtime.h>
#include <cstdint>
#include <cmath>

#define T_TOK 8192
#define H_DIM 1024
#define F_DIM 4096
#define NE 8
#define CAP 8192        // perm capacity per expert
#define BK 64
#define MBLK 32         // max M-blocks (128-row) per expert (4096-token cap)

typedef __attribute__((ext_vector_type(8))) short short8v;
typedef __attribute__((ext_vector_type(4))) float f32x4;

static __device__ __forceinline__ unsigned short f2bf(float f) {
    union { float f; unsigned int u; } v; v.f = f;
    unsigned int r = v.u + 0x7FFFu + ((v.u >> 16) & 1u);  // RNE
    return (unsigned short)(r >> 16);
}

// async global->LDS, 16B per lane; LDS dest is wave-uniform base + lane*16,
// global src is per-lane (supports gather + pre-swizzled source).
static __device__ __forceinline__ void gl_lds16(const void* g, void* l) {
    __builtin_amdgcn_global_load_lds(
        (const __attribute__((address_space(1))) unsigned int*)g,
        (__attribute__((address_space(3))) unsigned int*)l, 16, 0, 0);
}

// ---------------- router: logits, top-2, weights, compaction, inverse map, x->bf16 ----------------
__global__ void router_k(const float* __restrict__ x, const float* __restrict__ Wr,
                         const float* __restrict__ br,
                         int* __restrict__ cnt, int* __restrict__ perm, float* __restrict__ pw,
                         int* __restrict__ inv, float* __restrict__ tw,
                         unsigned short* __restrict__ xb)
{
    const int wave = threadIdx.x >> 6;
    const int lane = threadIdx.x & 63;
    const int t = blockIdx.x * 4 + wave;
    const float* xr = x + (size_t)t * H_DIM;
    float acc[NE];
#pragma unroll
    for (int e = 0; e < NE; ++e) acc[e] = 0.f;
#pragma unroll
    for (int c0 = 0; c0 < H_DIM; c0 += 256) {
        const float4 v = *(const float4*)(xr + c0 + lane * 4);
        ushort4 ob;
        ob.x = f2bf(v.x); ob.y = f2bf(v.y); ob.z = f2bf(v.z); ob.w = f2bf(v.w);
        *(ushort4*)(xb + (size_t)t * H_DIM + c0 + lane * 4) = ob;
        const int hbase = c0 + lane * 4;
        float vv[4] = {v.x, v.y, v.z, v.w};
#pragma unroll
        for (int i = 0; i < 4; ++i) {
            const float4 w0 = *(const float4*)(Wr + (size_t)(hbase + i) * NE);
            const float4 w1 = *(const float4*)(Wr + (size_t)(hbase + i) * NE + 4);
            acc[0] += vv[i] * w0.x; acc[1] += vv[i] * w0.y;
            acc[2] += vv[i] * w0.z; acc[3] += vv[i] * w0.w;
            acc[4] += vv[i] * w1.x; acc[5] += vv[i] * w1.y;
            acc[6] += vv[i] * w1.z; acc[7] += vv[i] * w1.w;
        }
    }
#pragma unroll
    for (int off = 32; off > 0; off >>= 1) {
#pragma unroll
        for (int e = 0; e < NE; ++e) acc[e] += __shfl_xor(acc[e], off, 64);
    }
    if (lane == 0) {
#pragma unroll
        for (int e = 0; e < NE; ++e) acc[e] += br[e];
        int i0 = 0; float l0 = acc[0];
#pragma unroll
        for (int e = 1; e < NE; ++e) if (acc[e] > l0) { l0 = acc[e]; i0 = e; }
        int i1 = -1; float l1 = -3.4e38f;
#pragma unroll
        for (int e = 0; e < NE; ++e) if (e != i0 && acc[e] > l1) { l1 = acc[e]; i1 = e; }
        // top-2 renormalized softmax weights from logits (exact)
        const float w0 = 1.f / (1.f + expf(l1 - l0));
        const int p0 = atomicAdd(&cnt[i0], 1);
        perm[i0 * CAP + p0] = t; pw[i0 * CAP + p0] = w0;
        const int p1 = atomicAdd(&cnt[i1], 1);
        perm[i1 * CAP + p1] = t; pw[i1 * CAP + p1] = 1.f - w0;
        inv[2 * t + 0] = (i0 << 13) | p0;  tw[2 * t + 0] = w0;
        inv[2 * t + 1] = (i1 << 13) | p1;  tw[2 * t + 1] = 1.f - w0;
    }
}

// ---------------- 128-aligned exclusive prefix of counts ----------------
__global__ void prefix_k(const int* __restrict__ cnt, int* __restrict__ offs)
{
    if (threadIdx.x == 0 && blockIdx.x == 0) {
        int o = 0;
        for (int e = 0; e < NE; ++e) { offs[e] = o; o += ((cnt[e] + 127) >> 7) << 7; }
        offs[NE] = o;
    }
}

// ---------------- transpose + fp32->bf16 convert: in[E][R][C] -> out[E][C][R] ----------------
__global__ __launch_bounds__(256) void tcvt_k(const float* __restrict__ in,
                                              unsigned short* __restrict__ out,
                                              int R, int C)
{
    __shared__ float tile[64][65];
    const int e = blockIdx.z;
    const int r0 = blockIdx.y * 64, c0 = blockIdx.x * 64;
    const float* ip = in + (size_t)e * R * C;
    unsigned short* op = out + (size_t)e * R * C;
    const int j = threadIdx.x;
    const int lr = j >> 4, lc = (j & 15) * 4;
#pragma unroll
    for (int p = 0; p < 4; ++p) {
        const float4 v = *(const float4*)(ip + (size_t)(r0 + lr + p * 16) * C + c0 + lc);
        tile[lr + p * 16][lc + 0] = v.x;
        tile[lr + p * 16][lc + 1] = v.y;
        tile[lr + p * 16][lc + 2] = v.z;
        tile[lr + p * 16][lc + 3] = v.w;
    }
    __syncthreads();
#pragma unroll
    for (int p = 0; p < 4; ++p) {
        const int orow = lr + p * 16;
        ushort4 o;
        o.x = f2bf(tile[lc + 0][orow]);
        o.y = f2bf(tile[lc + 1][orow]);
        o.z = f2bf(tile[lc + 2][orow]);
        o.w = f2bf(tile[lc + 3][orow]);
        *(ushort4*)(op + (size_t)(c0 + orow) * R + r0 + lc) = o;
    }
}

// ================= GEMM1: h = gelu(gather(x) @ W1[e] + b1[e]) =================
// 128x128 tile, 4 waves, BK=64, global_load_lds, DOUBLE-buffered LDS with
// prefetch-before-compute (drain lands after compute), XOR-swizzled src+read,
// swapped-operand MFMA -> packed 8B stores along f.
__global__ __launch_bounds__(256, 2) void gemm1_k(
    const unsigned short* __restrict__ xb,   // [T][H] bf16
    const unsigned short* __restrict__ w1t,  // [E][F][H] bf16 (pre-transposed)
    const float* __restrict__ b1,            // [E][F]
    unsigned short* __restrict__ hbuf,       // [rows][F] bf16
    const int* __restrict__ perm, const int* __restrict__ cnt, const int* __restrict__ offs)
{
    __shared__ __align__(16) unsigned short smem[32768];  // 64KB: 2 bufs x (A 8192 | B 8192)
    __shared__ int rows_s[128];

    constexpr int NY = F_DIM / 128;            // 32
    constexpr int nwg = MBLK * NY * NE;        // 8192
    const int bid = blockIdx.x;
    const int wg = (bid & 7) * (nwg >> 3) + (bid >> 3);   // XCD-aware bijective swizzle
    const int e  = wg / (MBLK * NY);
    const int rem = wg % (MBLK * NY);
    const int nb = rem / MBLK;
    const int mb = rem % MBLK;                 // fastest: same-XCD neighbors share B panel

    const int c = cnt[e];
    const int m0 = mb * 128;
    if (m0 >= c) return;
    const int tid = threadIdx.x;

    if (tid < 128) {
        const int i = m0 + tid;
        rows_s[tid] = perm[e * CAP + (i < c ? i : c - 1)];
    }
    __syncthreads();

    const int lane = tid & 63;
    const int w = tid >> 6;            // wave 0..3 (stages rows [w*32, w*32+32))
    const int lr8 = lane >> 3;
    const int u = lane & 7;

    const unsigned short* bp = w1t + ((size_t)e * F_DIM + nb * 128) * H_DIM;
    const unsigned short* srcA[4];
    const unsigned short* srcB[4];
    int dstA[4], dstB[4];
#pragma unroll
    for (int j = 0; j < 4; ++j) {
        const int r = w * 32 + j * 8 + lr8;
        const int us = (u ^ (r & 7)) * 8;      // pre-swizzled source unit
        srcA[j] = xb + (size_t)rows_s[r] * H_DIM + us;
        srcB[j] = bp + (size_t)r * H_DIM + us;
        dstA[j] = (w * 32 + j * 8) * BK + lane * 8;          // wave-uniform LDS base
        dstB[j] = 8192 + (w * 32 + j * 8) * BK + lane * 8;
    }

    f32x4 acc[4][4];
#pragma unroll
    for (int m = 0; m < 4; ++m)
#pragma unroll
        for (int n = 0; n < 4; ++n) acc[m][n] = (f32x4){0.f, 0.f, 0.f, 0.f};

    const int wr = (tid >> 7) & 1;     // token half
    const int wc = (tid >> 6) & 1;     // f half
    const int fr = lane & 15;
    const int fg = lane >> 4;
    const int fx = fr & 7;

    constexpr int NT = H_DIM / BK;     // 16
    // prologue: stage tile 0 into buf 0
#pragma unroll
    for (int j = 0; j < 4; ++j) gl_lds16(srcA[j], smem + dstA[j]);
#pragma unroll
    for (int j = 0; j < 4; ++j) gl_lds16(srcB[j], smem + dstB[j]);
    __syncthreads();

    for (int t = 0; t < NT; ++t) {
        if (t + 1 < NT) {              // prefetch next tile into other buf
            const int o = ((t + 1) & 1) << 14;
            const int k0 = (t + 1) * BK;
#pragma unroll
            for (int j = 0; j < 4; ++j) gl_lds16(srcA[j] + k0, smem + o + dstA[j]);
#pragma unroll
            for (int j = 0; j < 4; ++j) gl_lds16(srcB[j] + k0, smem + o + dstB[j]);
        }
        const unsigned short* A = smem + ((t & 1) << 14);
        const unsigned short* B = A + 8192;
#pragma unroll
        for (int kk = 0; kk < 2; ++kk) {
            const int q = kk * 4 + fg;
            const int ua = (q ^ fx) * 8;
            short8v a[4], b[4];
#pragma unroll
            for (int m = 0; m < 4; ++m)
                a[m] = *(const short8v*)(A + (wr * 64 + m * 16 + fr) * BK + ua);
#pragma unroll
            for (int n = 0; n < 4; ++n)
                b[n] = *(const short8v*)(B + (wc * 64 + n * 16 + fr) * BK + ua);
#pragma unroll
            for (int m = 0; m < 4; ++m)
#pragma unroll
                for (int n = 0; n < 4; ++n)   // swapped: C[f][token]
                    acc[m][n] = __builtin_amdgcn_mfma_f32_16x16x32_bf16(b[n], a[m], acc[m][n], 0, 0, 0);
        }
        __syncthreads();               // drain (after compute) + buffer handoff
    }

    // epilogue: thread holds 4 consecutive f at fixed token -> packed 8B stores
    const size_t hrow0 = (size_t)offs[e] + m0;
#pragma unroll
    for (int n = 0; n < 4; ++n) {
        const int f = nb * 128 + wc * 64 + n * 16 + fg * 4;
        const float4 bv = *(const float4*)(b1 + e * F_DIM + f);
        const float bb[4] = {bv.x, bv.y, bv.z, bv.w};
#pragma unroll
        for (int m = 0; m < 4; ++m) {
            const int tl = wr * 64 + m * 16 + fr;
            ushort4 o;
#pragma unroll
            for (int r = 0; r < 4; ++r) {
                const float xv = acc[m][n][r] + bb[r];
                const float g = 0.5f * xv * (1.f + erff(xv * 0.70710678118f));
                ((unsigned short*)&o)[r] = f2bf(g);
            }
            *(ushort4*)(hbuf + (hrow0 + tl) * F_DIM + f) = o;
        }
    }
}

// ================= GEMM2: ybuf[row] = h @ W2[e] + b2[e] (fp32, no atomics) =================
__global__ __launch_bounds__(256, 2) void gemm2_k(
    const unsigned short* __restrict__ hbuf, // [rows][F] bf16
    const unsigned short* __restrict__ w2t,  // [E][H][F] bf16 (pre-transposed)
    const float* __restrict__ b2,            // [E][H]
    float* __restrict__ ybuf,                // [rows][H] fp32
    const int* __restrict__ cnt, const int* __restrict__ offs)
{
    __shared__ __align__(16) unsigned short smem[32768];

    constexpr int NY = H_DIM / 128;            // 8
    constexpr int nwg = MBLK * NY * NE;        // 2048
    const int bid = blockIdx.x;
    const int wg = (bid & 7) * (nwg >> 3) + (bid >> 3);
    const int e  = wg / (MBLK * NY);
    const int rem = wg % (MBLK * NY);
    const int nb = rem / MBLK;
    const int mb = rem % MBLK;

    const int c = cnt[e];
    const int m0 = mb * 128;
    if (m0 >= c) return;
    const int tid = threadIdx.x;

    const int lane = tid & 63;
    const int w = tid >> 6;
    const int lr8 = lane >> 3;
    const int u = lane & 7;

    const size_t arow0 = (size_t)offs[e] + m0;
    const unsigned short* bp = w2t + ((size_t)e * H_DIM + nb * 128) * F_DIM;
    const unsigned short* srcA[4];
    const unsigned short* srcB[4];
    int dstA[4], dstB[4];
#pragma unroll
    for (int j = 0; j < 4; ++j) {
        const int r = w * 32 + j * 8 + lr8;
        const int us = (u ^ (r & 7)) * 8;
        srcA[j] = hbuf + (arow0 + r) * F_DIM + us;
        srcB[j] = bp + (size_t)r * F_DIM + us;
        dstA[j] = (w * 32 + j * 8) * BK + lane * 8;
        dstB[j] = 8192 + (w * 32 + j * 8) * BK + lane * 8;
    }

    f32x4 acc[4][4];
#pragma unroll
    for (int m = 0; m < 4; ++m)
#pragma unroll
        for (int n = 0; n < 4; ++n) acc[m][n] = (f32x4){0.f, 0.f, 0.f, 0.f};

    const int wr = (tid >> 7) & 1;
    const int wc = (tid >> 6) & 1;
    const int fr = lane & 15;
    const int fg = lane >> 4;
    const int fx = fr & 7;

    constexpr int NT = F_DIM / BK;     // 64
#pragma unroll
    for (int j = 0; j < 4; ++j) gl_lds16(srcA[j], smem + dstA[j]);
#pragma unroll
    for (int j = 0; j < 4; ++j) gl_lds16(srcB[j], smem + dstB[j]);
    __syncthreads();

    for (int t = 0; t < NT; ++t) {
        if (t + 1 < NT) {
            const int o = ((t + 1) & 1) << 14;
            const int k0 = (t + 1) * BK;
#pragma unroll
            for (int j = 0; j < 4; ++j) gl_lds16(srcA[j] + k0, smem + o + dstA[j]);
#pragma unroll
            for (int j = 0; j < 4; ++j) gl_lds16(srcB[j] + k0, smem + o + dstB[j]);
        }
        const unsigned short* A = smem + ((t & 1) << 14);
        const unsigned short* B = A + 8192;
#pragma unroll
        for (int kk = 0; kk < 2; ++kk) {
            const int q = kk * 4 + fg;
            const int ua = (q ^ fx) * 8;
            short8v a[4], b[4];
#pragma unroll
            for (int m = 0; m < 4; ++m)
                a[m] = *(const short8v*)(A + (wr * 64 + m * 16 + fr) * BK + ua);
#pragma unroll
            for (int n = 0; n < 4; ++n)
                b[n] = *(const short8v*)(B + (wc * 64 + n * 16 + fr) * BK + ua);
#pragma unroll
            for (int m = 0; m < 4; ++m)
#pragma unroll
                for (int n = 0; n < 4; ++n)
                    acc[m][n] = __builtin_amdgcn_mfma_f32_16x16x32_bf16(b[n], a[m], acc[m][n], 0, 0, 0);
        }
        __syncthreads();
    }

    // epilogue: packed float4 stores (bias folded, weights applied in combine_k)
#pragma unroll
    for (int n = 0; n < 4; ++n) {
        const int h = nb * 128 + wc * 64 + n * 16 + fg * 4;
        const float4 bv = *(const float4*)(b2 + e * H_DIM + h);
#pragma unroll
        for (int m = 0; m < 4; ++m) {
            const int tl = wr * 64 + m * 16 + fr;
            float4 o;
            o.x = acc[m][n][0] + bv.x;
            o.y = acc[m][n][1] + bv.y;
            o.z = acc[m][n][2] + bv.z;
            o.w = acc[m][n][3] + bv.w;
            *(float4*)(ybuf + (arow0 + tl) * H_DIM + h) = o;
        }
    }
}

// ---------------- combine: out[t] = w0*y[slot0] + w1*y[slot1] ----------------
__global__ __launch_bounds__(256) void combine_k(
    const float* __restrict__ ybuf, const int* __restrict__ inv,
    const float* __restrict__ tw, const int* __restrict__ offs,
    float* __restrict__ out)
{
    const int t = blockIdx.x;
    const int j = threadIdx.x;          // 256 threads x float4 = 1024 = H
    const int i0 = inv[2 * t], i1 = inv[2 * t + 1];
    const float w0 = tw[2 * t], w1 = tw[2 * t + 1];
    const size_t r0 = (size_t)offs[i0 >> 13] + (i0 & 8191);
    const size_t r1 = (size_t)offs[i1 >> 13] + (i1 & 8191);
    const float4 a = *(const float4*)(ybuf + r0 * H_DIM + j * 4);
    const float4 b = *(const float4*)(ybuf + r1 * H_DIM + j * 4);
    float4 o;
    o.x = w0 * a.x + w1 * b.x;
    o.y = w0 * a.y + w1 * b.y;
    o.z = w0 * a.z + w1 * b.z;
    o.w = w0 * a.w + w1 * b.w;
    *(float4*)(out + (size_t)t * H_DIM + j * 4) = o;
}

extern "C" void kernel_launch(void* const* d_in, const int* in_sizes, int n_in,
                              void* d_out, int out_size, void* d_ws, size_t ws_size,
                              hipStream_t stream)
{
    const float* x  = (const float*)d_in[0];
    const float* Wr = (const float*)d_in[1];
    const float* br = (const float*)d_in[2];
    const float* W1 = (const float*)d_in[3];
    const float* b1 = (const float*)d_in[4];
    const float* W2 = (const float*)d_in[5];
    const float* b2 = (const float*)d_in[6];
    float* out = (float*)d_out;

    char* ws = (char*)d_ws;
    size_t off = 0;
    auto alloc = [&](size_t bytes) {
        char* p = ws + off;
        off += (bytes + 255) & ~(size_t)255;
        return p;
    };
    // Order matters: ybuf aliases [w1t, xb] (dead after gemm1 completes).
    unsigned short* w2t  = (unsigned short*)alloc((size_t)NE * H_DIM * F_DIM * 2);  // 67 MB
    unsigned short* w1t  = (unsigned short*)alloc((size_t)NE * F_DIM * H_DIM * 2);  // 67 MB
    unsigned short* xb   = (unsigned short*)alloc((size_t)T_TOK * H_DIM * 2);       // 17 MB
    unsigned short* hbuf = (unsigned short*)alloc((size_t)(T_TOK * 2 + NE * 128) * F_DIM * 2); // 143 MB
    int*   cnt  = (int*)alloc(NE * 4);
    int*   offs = (int*)alloc((NE + 1) * 4);
    int*   perm = (int*)alloc((size_t)NE * CAP * 4);
    float* pw   = (float*)alloc((size_t)NE * CAP * 4);
    int*   inv  = (int*)alloc((size_t)T_TOK * 2 * 4);
    float* tw   = (float*)alloc((size_t)T_TOK * 2 * 4);
    float* ybuf = (float*)w1t;   // [rows][H] fp32, 71 MB < w1t+xb (84 MB)
    (void)ws_size; (void)in_sizes; (void)n_in; (void)out_size;

    hipMemsetAsync(cnt, 0, NE * 4, stream);
    router_k<<<T_TOK / 4, 256, 0, stream>>>(x, Wr, br, cnt, perm, pw, inv, tw, xb);
    prefix_k<<<1, 64, 0, stream>>>(cnt, offs);
    tcvt_k<<<dim3(F_DIM / 64, H_DIM / 64, NE), 256, 0, stream>>>(W1, w1t, H_DIM, F_DIM);
    tcvt_k<<<dim3(H_DIM / 64, F_DIM / 64, NE), 256, 0, stream>>>(W2, w2t, F_DIM, H_DIM);
    gemm1_k<<<MBLK * (F_DIM / 128) * NE, 256, 0, stream>>>(xb, w1t, b1, hbuf, perm, cnt, offs);
    gemm2_k<<<MBLK * (H_DIM / 128) * NE, 256, 0, stream>>>(hbuf, w2t, b2, ybuf, cnt, offs);
    combine_k<<<T_TOK, 256, 0, stream>>>(ybuf, inv, tw, offs, out);
}

// Round 6
// 774.332 us; speedup vs baseline: 1.4227x; 1.0541x over previous
//
#include <hip/hip_runtime.h>
#include <cstdint>
#include <cmath>

#define T_TOK 8192
#define H_DIM 1024
#define F_DIM 4096
#define NE 8
#define CAP 8192        // perm capacity per expert
#define BK 64
#define BM 128          // token rows per block
#define BN 256          // output cols per block
#define MBLK 32         // max M-blocks (128-row) per expert (4096-token cap)

typedef __attribute__((ext_vector_type(8))) short short8v;
typedef __attribute__((ext_vector_type(4))) float f32x4;

static __device__ __forceinline__ unsigned short f2bf(float f) {
    union { float f; unsigned int u; } v; v.f = f;
    unsigned int r = v.u + 0x7FFFu + ((v.u >> 16) & 1u);  // RNE
    return (unsigned short)(r >> 16);
}

// async global->LDS, 16B per lane; LDS dest is wave-uniform base + lane*16,
// global src is per-lane (supports gather + pre-swizzled source).
static __device__ __forceinline__ void gl_lds16(const void* g, void* l) {
    __builtin_amdgcn_global_load_lds(
        (const __attribute__((address_space(1))) unsigned int*)g,
        (__attribute__((address_space(3))) unsigned int*)l, 16, 0, 0);
}

// ---------------- router: logits, top-2, weights, compaction, inverse map, x->bf16 ----------------
__global__ void router_k(const float* __restrict__ x, const float* __restrict__ Wr,
                         const float* __restrict__ br,
                         int* __restrict__ cnt, int* __restrict__ perm,
                         int* __restrict__ inv, float* __restrict__ tw,
                         unsigned short* __restrict__ xb)
{
    const int wave = threadIdx.x >> 6;
    const int lane = threadIdx.x & 63;
    const int t = blockIdx.x * 4 + wave;
    const float* xr = x + (size_t)t * H_DIM;
    float acc[NE];
#pragma unroll
    for (int e = 0; e < NE; ++e) acc[e] = 0.f;
#pragma unroll
    for (int c0 = 0; c0 < H_DIM; c0 += 256) {
        const float4 v = *(const float4*)(xr + c0 + lane * 4);
        ushort4 ob;
        ob.x = f2bf(v.x); ob.y = f2bf(v.y); ob.z = f2bf(v.z); ob.w = f2bf(v.w);
        *(ushort4*)(xb + (size_t)t * H_DIM + c0 + lane * 4) = ob;
        const int hbase = c0 + lane * 4;
        float vv[4] = {v.x, v.y, v.z, v.w};
#pragma unroll
        for (int i = 0; i < 4; ++i) {
            const float4 w0 = *(const float4*)(Wr + (size_t)(hbase + i) * NE);
            const float4 w1 = *(const float4*)(Wr + (size_t)(hbase + i) * NE + 4);
            acc[0] += vv[i] * w0.x; acc[1] += vv[i] * w0.y;
            acc[2] += vv[i] * w0.z; acc[3] += vv[i] * w0.w;
            acc[4] += vv[i] * w1.x; acc[5] += vv[i] * w1.y;
            acc[6] += vv[i] * w1.z; acc[7] += vv[i] * w1.w;
        }
    }
#pragma unroll
    for (int off = 32; off > 0; off >>= 1) {
#pragma unroll
        for (int e = 0; e < NE; ++e) acc[e] += __shfl_xor(acc[e], off, 64);
    }
    if (lane == 0) {
#pragma unroll
        for (int e = 0; e < NE; ++e) acc[e] += br[e];
        int i0 = 0; float l0 = acc[0];
#pragma unroll
        for (int e = 1; e < NE; ++e) if (acc[e] > l0) { l0 = acc[e]; i0 = e; }
        int i1 = -1; float l1 = -3.4e38f;
#pragma unroll
        for (int e = 0; e < NE; ++e) if (e != i0 && acc[e] > l1) { l1 = acc[e]; i1 = e; }
        // top-2 renormalized softmax weights from logits (exact)
        const float w0 = 1.f / (1.f + expf(l1 - l0));
        const int p0 = atomicAdd(&cnt[i0], 1);
        perm[i0 * CAP + p0] = t;
        const int p1 = atomicAdd(&cnt[i1], 1);
        perm[i1 * CAP + p1] = t;
        inv[2 * t + 0] = (i0 << 13) | p0;  tw[2 * t + 0] = w0;
        inv[2 * t + 1] = (i1 << 13) | p1;  tw[2 * t + 1] = 1.f - w0;
    }
}

// ---------------- 128-aligned exclusive prefix of counts ----------------
__global__ void prefix_k(const int* __restrict__ cnt, int* __restrict__ offs)
{
    if (threadIdx.x == 0 && blockIdx.x == 0) {
        int o = 0;
        for (int e = 0; e < NE; ++e) { offs[e] = o; o += ((cnt[e] + 127) >> 7) << 7; }
        offs[NE] = o;
    }
}

// ---------------- transpose + fp32->bf16 convert: in[E][R][C] -> out[E][C][R] ----------------
__global__ __launch_bounds__(256) void tcvt_k(const float* __restrict__ in,
                                              unsigned short* __restrict__ out,
                                              int R, int C)
{
    __shared__ float tile[64][65];
    const int e = blockIdx.z;
    const int r0 = blockIdx.y * 64, c0 = blockIdx.x * 64;
    const float* ip = in + (size_t)e * R * C;
    unsigned short* op = out + (size_t)e * R * C;
    const int j = threadIdx.x;
    const int lr = j >> 4, lc = (j & 15) * 4;
#pragma unroll
    for (int p = 0; p < 4; ++p) {
        const float4 v = *(const float4*)(ip + (size_t)(r0 + lr + p * 16) * C + c0 + lc);
        tile[lr + p * 16][lc + 0] = v.x;
        tile[lr + p * 16][lc + 1] = v.y;
        tile[lr + p * 16][lc + 2] = v.z;
        tile[lr + p * 16][lc + 3] = v.w;
    }
    __syncthreads();
#pragma unroll
    for (int p = 0; p < 4; ++p) {
        const int orow = lr + p * 16;
        ushort4 o;
        o.x = f2bf(tile[lc + 0][orow]);
        o.y = f2bf(tile[lc + 1][orow]);
        o.z = f2bf(tile[lc + 2][orow]);
        o.w = f2bf(tile[lc + 3][orow]);
        *(ushort4*)(op + (size_t)(c0 + orow) * R + r0 + lc) = o;
    }
}

// ================= GEMM1: h = gelu(gather(x) @ W1[e] + b1[e]) =================
// 128x256 tile, 4 waves (2M x 2N), wave-tile 64x128: a[4] x b[8] -> 64 MFMA per
// K-step per wave vs 12 ds_read_b128 (2x density of the 64x64 wave tile).
// Single-buffer BK=64 (48KB LDS, >=2 blocks/CU), global_load_lds staging,
// XOR-swizzled source+read, swapped-operand MFMA -> packed 8B stores along f.
__global__ __launch_bounds__(256, 2) void gemm1_k(
    const unsigned short* __restrict__ xb,   // [T][H] bf16
    const unsigned short* __restrict__ w1t,  // [E][F][H] bf16 (pre-transposed)
    const float* __restrict__ b1,            // [E][F]
    unsigned short* __restrict__ hbuf,       // [rows][F] bf16
    const int* __restrict__ perm, const int* __restrict__ cnt, const int* __restrict__ offs)
{
    __shared__ __align__(16) unsigned short smem[(BM + BN) * BK];  // A 16KB | B 32KB
    __shared__ int rows_s[BM];

    constexpr int NY = F_DIM / BN;             // 16
    constexpr int nwg = MBLK * NY * NE;        // 4096
    const int bid = blockIdx.x;
    const int wg = (bid & 7) * (nwg >> 3) + (bid >> 3);   // XCD-aware bijective swizzle
    const int e  = wg / (MBLK * NY);
    const int rem = wg % (MBLK * NY);
    const int nb = rem / MBLK;
    const int mb = rem % MBLK;                 // fastest: same-XCD neighbors share B panel

    const int c = cnt[e];
    const int m0 = mb * BM;
    if (m0 >= c) return;
    const int tid = threadIdx.x;

    if (tid < BM) {
        const int i = m0 + tid;
        rows_s[tid] = perm[e * CAP + (i < c ? i : c - 1)];
    }
    __syncthreads();

    const int lane = tid & 63;
    const int w = tid >> 6;            // wave 0..3
    const int srow = tid >> 3;         // staging row-in-issue 0..31
    const int u = tid & 7;             // 16B unit within 128B row
    const int us = (u ^ (srow & 7)) * 8;   // pre-swizzled source unit (shorts)

    const unsigned short* bp = w1t + ((size_t)e * F_DIM + nb * BN) * H_DIM;
    const unsigned short* srcA[4];
    const unsigned short* srcB[8];
    int dstA[4], dstB[8];
#pragma unroll
    for (int j = 0; j < 4; ++j) {
        srcA[j] = xb + (size_t)rows_s[j * 32 + srow] * H_DIM + us;
        dstA[j] = (j * 32 + w * 8) * BK + lane * 8;          // wave-uniform LDS base
    }
#pragma unroll
    for (int j = 0; j < 8; ++j) {
        srcB[j] = bp + (size_t)(j * 32 + srow) * H_DIM + us;
        dstB[j] = BM * BK + (j * 32 + w * 8) * BK + lane * 8;
    }

    f32x4 acc[4][8];
#pragma unroll
    for (int m = 0; m < 4; ++m)
#pragma unroll
        for (int n = 0; n < 8; ++n) acc[m][n] = (f32x4){0.f, 0.f, 0.f, 0.f};

    const int wm = w >> 1;             // token half (0..1)
    const int wn = w & 1;              // f half (0..1)
    const int fr = lane & 15;
    const int fg = lane >> 4;
    const int fx = fr & 7;

    for (int k0 = 0; k0 < H_DIM; k0 += BK) {
#pragma unroll
        for (int j = 0; j < 4; ++j) gl_lds16(srcA[j] + k0, smem + dstA[j]);
#pragma unroll
        for (int j = 0; j < 8; ++j) gl_lds16(srcB[j] + k0, smem + dstB[j]);
        __syncthreads();   // drains vmcnt + barrier
        const unsigned short* A = smem;
        const unsigned short* B = smem + BM * BK;
#pragma unroll
        for (int kk = 0; kk < 2; ++kk) {
            const int q = kk * 4 + fg;
            const int ua = (q ^ fx) * 8;
            short8v a[4], b[8];
#pragma unroll
            for (int m = 0; m < 4; ++m)
                a[m] = *(const short8v*)(A + (wm * 64 + m * 16 + fr) * BK + ua);
#pragma unroll
            for (int n = 0; n < 8; ++n)
                b[n] = *(const short8v*)(B + (wn * 128 + n * 16 + fr) * BK + ua);
#pragma unroll
            for (int m = 0; m < 4; ++m)
#pragma unroll
                for (int n = 0; n < 8; ++n)   // swapped: C[f][token]
                    acc[m][n] = __builtin_amdgcn_mfma_f32_16x16x32_bf16(b[n], a[m], acc[m][n], 0, 0, 0);
        }
        __syncthreads();
    }

    // epilogue: thread holds 4 consecutive f at fixed token -> packed 8B stores
    const size_t hrow0 = (size_t)offs[e] + m0;
#pragma unroll
    for (int n = 0; n < 8; ++n) {
        const int f = nb * BN + wn * 128 + n * 16 + fg * 4;
        const float4 bv = *(const float4*)(b1 + e * F_DIM + f);
        const float bb[4] = {bv.x, bv.y, bv.z, bv.w};
#pragma unroll
        for (int m = 0; m < 4; ++m) {
            const int tl = wm * 64 + m * 16 + fr;
            ushort4 o;
#pragma unroll
            for (int r = 0; r < 4; ++r) {
                const float xv = acc[m][n][r] + bb[r];
                const float g = 0.5f * xv * (1.f + erff(xv * 0.70710678118f));
                ((unsigned short*)&o)[r] = f2bf(g);
            }
            *(ushort4*)(hbuf + (hrow0 + tl) * F_DIM + f) = o;
        }
    }
}

// ================= GEMM2: ybuf[row] = h @ W2[e] + b2[e] (fp32, no atomics) =================
__global__ __launch_bounds__(256, 2) void gemm2_k(
    const unsigned short* __restrict__ hbuf, // [rows][F] bf16
    const unsigned short* __restrict__ w2t,  // [E][H][F] bf16 (pre-transposed)
    const float* __restrict__ b2,            // [E][H]
    float* __restrict__ ybuf,                // [rows][H] fp32
    const int* __restrict__ cnt, const int* __restrict__ offs)
{
    __shared__ __align__(16) unsigned short smem[(BM + BN) * BK];

    constexpr int NY = H_DIM / BN;             // 4
    constexpr int nwg = MBLK * NY * NE;        // 1024
    const int bid = blockIdx.x;
    const int wg = (bid & 7) * (nwg >> 3) + (bid >> 3);
    const int e  = wg / (MBLK * NY);
    const int rem = wg % (MBLK * NY);
    const int nb = rem / MBLK;
    const int mb = rem % MBLK;

    const int c = cnt[e];
    const int m0 = mb * BM;
    if (m0 >= c) return;
    const int tid = threadIdx.x;

    const int lane = tid & 63;
    const int w = tid >> 6;
    const int srow = tid >> 3;
    const int u = tid & 7;
    const int us = (u ^ (srow & 7)) * 8;

    const size_t arow0 = (size_t)offs[e] + m0;
    const unsigned short* bp = w2t + ((size_t)e * H_DIM + nb * BN) * F_DIM;
    const unsigned short* srcA[4];
    const unsigned short* srcB[8];
    int dstA[4], dstB[8];
#pragma unroll
    for (int j = 0; j < 4; ++j) {
        srcA[j] = hbuf + (arow0 + j * 32 + srow) * F_DIM + us;
        dstA[j] = (j * 32 + w * 8) * BK + lane * 8;
    }
#pragma unroll
    for (int j = 0; j < 8; ++j) {
        srcB[j] = bp + (size_t)(j * 32 + srow) * F_DIM + us;
        dstB[j] = BM * BK + (j * 32 + w * 8) * BK + lane * 8;
    }

    f32x4 acc[4][8];
#pragma unroll
    for (int m = 0; m < 4; ++m)
#pragma unroll
        for (int n = 0; n < 8; ++n) acc[m][n] = (f32x4){0.f, 0.f, 0.f, 0.f};

    const int wm = w >> 1;
    const int wn = w & 1;
    const int fr = lane & 15;
    const int fg = lane >> 4;
    const int fx = fr & 7;

    for (int k0 = 0; k0 < F_DIM; k0 += BK) {
#pragma unroll
        for (int j = 0; j < 4; ++j) gl_lds16(srcA[j] + k0, smem + dstA[j]);
#pragma unroll
        for (int j = 0; j < 8; ++j) gl_lds16(srcB[j] + k0, smem + dstB[j]);
        __syncthreads();
        const unsigned short* A = smem;
        const unsigned short* B = smem + BM * BK;
#pragma unroll
        for (int kk = 0; kk < 2; ++kk) {
            const int q = kk * 4 + fg;
            const int ua = (q ^ fx) * 8;
            short8v a[4], b[8];
#pragma unroll
            for (int m = 0; m < 4; ++m)
                a[m] = *(const short8v*)(A + (wm * 64 + m * 16 + fr) * BK + ua);
#pragma unroll
            for (int n = 0; n < 8; ++n)
                b[n] = *(const short8v*)(B + (wn * 128 + n * 16 + fr) * BK + ua);
#pragma unroll
            for (int m = 0; m < 4; ++m)
#pragma unroll
                for (int n = 0; n < 8; ++n)
                    acc[m][n] = __builtin_amdgcn_mfma_f32_16x16x32_bf16(b[n], a[m], acc[m][n], 0, 0, 0);
        }
        __syncthreads();
    }

    // epilogue: packed float4 stores (bias folded, weights applied in combine_k)
#pragma unroll
    for (int n = 0; n < 8; ++n) {
        const int h = nb * BN + wn * 128 + n * 16 + fg * 4;
        const float4 bv = *(const float4*)(b2 + e * H_DIM + h);
#pragma unroll
        for (int m = 0; m < 4; ++m) {
            const int tl = wm * 64 + m * 16 + fr;
            float4 o;
            o.x = acc[m][n][0] + bv.x;
            o.y = acc[m][n][1] + bv.y;
            o.z = acc[m][n][2] + bv.z;
            o.w = acc[m][n][3] + bv.w;
            *(float4*)(ybuf + (arow0 + tl) * H_DIM + h) = o;
        }
    }
}

// ---------------- combine: out[t] = w0*y[slot0] + w1*y[slot1] ----------------
__global__ __launch_bounds__(256) void combine_k(
    const float* __restrict__ ybuf, const int* __restrict__ inv,
    const float* __restrict__ tw, const int* __restrict__ offs,
    float* __restrict__ out)
{
    const int t = blockIdx.x;
    const int j = threadIdx.x;          // 256 threads x float4 = 1024 = H
    const int i0 = inv[2 * t], i1 = inv[2 * t + 1];
    const float w0 = tw[2 * t], w1 = tw[2 * t + 1];
    const size_t r0 = (size_t)offs[i0 >> 13] + (i0 & 8191);
    const size_t r1 = (size_t)offs[i1 >> 13] + (i1 & 8191);
    const float4 a = *(const float4*)(ybuf + r0 * H_DIM + j * 4);
    const float4 b = *(const float4*)(ybuf + r1 * H_DIM + j * 4);
    float4 o;
    o.x = w0 * a.x + w1 * b.x;
    o.y = w0 * a.y + w1 * b.y;
    o.z = w0 * a.z + w1 * b.z;
    o.w = w0 * a.w + w1 * b.w;
    *(float4*)(out + (size_t)t * H_DIM + j * 4) = o;
}

extern "C" void kernel_launch(void* const* d_in, const int* in_sizes, int n_in,
                              void* d_out, int out_size, void* d_ws, size_t ws_size,
                              hipStream_t stream)
{
    const float* x  = (const float*)d_in[0];
    const float* Wr = (const float*)d_in[1];
    const float* br = (const float*)d_in[2];
    const float* W1 = (const float*)d_in[3];
    const float* b1 = (const float*)d_in[4];
    const float* W2 = (const float*)d_in[5];
    const float* b2 = (const float*)d_in[6];
    float* out = (float*)d_out;

    char* ws = (char*)d_ws;
    size_t off = 0;
    auto alloc = [&](size_t bytes) {
        char* p = ws + off;
        off += (bytes + 255) & ~(size_t)255;
        return p;
    };
    // Order matters: ybuf aliases [w1t, xb] (dead after gemm1 completes).
    unsigned short* w2t  = (unsigned short*)alloc((size_t)NE * H_DIM * F_DIM * 2);  // 67 MB
    unsigned short* w1t  = (unsigned short*)alloc((size_t)NE * F_DIM * H_DIM * 2);  // 67 MB
    unsigned short* xb   = (unsigned short*)alloc((size_t)T_TOK * H_DIM * 2);       // 17 MB
    unsigned short* hbuf = (unsigned short*)alloc((size_t)(T_TOK * 2 + NE * BM) * F_DIM * 2); // 143 MB
    int*   cnt  = (int*)alloc(NE * 4);
    int*   offs = (int*)alloc((NE + 1) * 4);
    int*   perm = (int*)alloc((size_t)NE * CAP * 4);
    int*   inv  = (int*)alloc((size_t)T_TOK * 2 * 4);
    float* tw   = (float*)alloc((size_t)T_TOK * 2 * 4);
    float* ybuf = (float*)w1t;   // [rows][H] fp32, 71 MB < w1t+xb (84 MB)
    (void)ws_size; (void)in_sizes; (void)n_in; (void)out_size;

    hipMemsetAsync(cnt, 0, NE * 4, stream);
    router_k<<<T_TOK / 4, 256, 0, stream>>>(x, Wr, br, cnt, perm, inv, tw, xb);
    prefix_k<<<1, 64, 0, stream>>>(cnt, offs);
    tcvt_k<<<dim3(F_DIM / 64, H_DIM / 64, NE), 256, 0, stream>>>(W1, w1t, H_DIM, F_DIM);
    tcvt_k<<<dim3(H_DIM / 64, F_DIM / 64, NE), 256, 0, stream>>>(W2, w2t, F_DIM, H_DIM);
    gemm1_k<<<MBLK * (F_DIM / BN) * NE, 256, 0, stream>>>(xb, w1t, b1, hbuf, perm, cnt, offs);
    gemm2_k<<<MBLK * (H_DIM / BN) * NE, 256, 0, stream>>>(hbuf, w2t, b2, ybuf, cnt, offs);
    combine_k<<<T_TOK, 256, 0, stream>>>(ybuf, inv, tw, offs, out);
}